// Round 14
// baseline (223.820 us; speedup 1.0000x reference)
//
#include <hip/hip_runtime.h>
#include <hip/hip_cooperative_groups.h>
#include <hip/hip_bf16.h>
#include <math.h>

namespace cg = cooperative_groups;

// Problem constants
#define BB 32
#define SS 16384
#define MM 64
#define HID 512
#define EPSV 1e-8f

typedef float nf4 __attribute__((ext_vector_type(4)));   // native vec for nt-store

// ws layout (in floats) — fallback (R10) regions:
#define OFF_H    0                 // 32*512 h vectors
#define OFF_P    16384             // 32*512 per-batch params
#define OFF_SGRP 32768             // BB*64 per-chunk wgam_r sums (fallback)
#define OFF_SGWP (OFF_SGRP + BB*64)
#define OFF_RP   (OFF_SGWP + BB*64)       // BB*64*64 r partials (fallback)
#define OFF_WGR  (OFF_RP + BB*64*64)      // BB*SS (fallback)
#define OFF_WGW  (OFF_WGR + BB*SS)
// cooperative-kernel regions (disjoint):
#define OFF_CSGR (OFF_WGW + BB*SS)        // BB*16 per-slab wgam_r sums
#define OFF_CSGW (OFF_CSGR + BB*16)
#define OFF_CRP  (OFF_CSGW + BB*16)       // BB*16*64 r partials
// end ≈ 5.0 MB of floats
//
// P-region per-batch layout (512 floats):
//  [0..63]   k_r            [64] beta_r  [69] gamma_r   [96..98] raw shift_r
//  [128..191] k_w           [192] beta_w [197] gamma_w  [224..226] raw shift_w
//  [256..319] erase         [320..383] add

__device__ __forceinline__ float sigmoidf_(float x) { return 1.f / (1.f + expf(-x)); }
__device__ __forceinline__ float softplusf_(float x) {
    return (x > 0.f) ? x + log1pf(expf(-x)) : log1pf(expf(x));
}

// One wave per (b,t): h[b][t].
__global__ void k_lstm(const float* __restrict__ x, const float* __restrict__ pdo,
                       const float* __restrict__ prv,
                       const float* __restrict__ W_ih, const float* __restrict__ b_ih,
                       const float* __restrict__ b_hh, float* __restrict__ ws) {
    int wid = blockIdx.x * 4 + (threadIdx.x >> 6);   // 0 .. 32*512-1
    int lane = threadIdx.x & 63;
    int b = wid >> 9, t = wid & 511;
    float x0 = x[b * 64 + lane];
    float x1 = pdo[b * 64 + lane];
    float x2 = prv[b * 64 + lane];
    const float* wi = W_ih + (size_t)t * 192;
    const float* wg = W_ih + (size_t)(1024 + t) * 192;
    const float* wo = W_ih + (size_t)(1536 + t) * 192;
    float zi = x0 * wi[lane] + x1 * wi[64 + lane] + x2 * wi[128 + lane];
    float zg = x0 * wg[lane] + x1 * wg[64 + lane] + x2 * wg[128 + lane];
    float zo = x0 * wo[lane] + x1 * wo[64 + lane] + x2 * wo[128 + lane];
    #pragma unroll
    for (int off = 32; off >= 1; off >>= 1) {
        zi += __shfl_xor(zi, off);
        zg += __shfl_xor(zg, off);
        zo += __shfl_xor(zo, off);
    }
    if (lane == 0) {
        zi += b_ih[t] + b_hh[t];
        zg += b_ih[1024 + t] + b_hh[1024 + t];
        zo += b_ih[1536 + t] + b_hh[1536 + t];
        float c = sigmoidf_(zi) * tanhf(zg);
        ws[OFF_H + (size_t)b * 512 + t] = sigmoidf_(zo) * tanhf(c);
    }
}

// One wave per (b, head-row j).
__global__ void k_heads(const float* __restrict__ W_r, const float* __restrict__ b_r,
                        const float* __restrict__ W_w, const float* __restrict__ b_w,
                        float* __restrict__ ws) {
    int wid = blockIdx.x * 4 + (threadIdx.x >> 6);   // 0 .. 32*268-1
    int lane = threadIdx.x & 63;
    int b = wid / 268, j = wid % 268;
    const float* h = ws + OFF_H + (size_t)b * 512;
    const float* wrow;
    float bias;
    if (j < 70) { wrow = W_r + (size_t)j * 512; bias = b_r[j]; }
    else        { wrow = W_w + (size_t)(j - 70) * 512; bias = b_w[j - 70]; }
    float acc = 0.f;
    #pragma unroll
    for (int c = 0; c < 8; c++) acc = fmaf(h[c * 64 + lane], wrow[c * 64 + lane], acc);
    #pragma unroll
    for (int off = 32; off >= 1; off >>= 1) acc += __shfl_xor(acc, off);
    if (lane != 0) return;
    acc += bias;
    float* P = ws + OFF_P + (size_t)b * 512;
    if (j < 70) {
        if (j < 64)       P[j] = acc;
        else if (j == 64) P[64] = softplusf_(acc);
        else if (j == 65) P[65] = sigmoidf_(acc);
        else if (j <= 68) P[96 + (j - 66)] = acc;
        else              P[69] = 1.f + softplusf_(acc);
    } else {
        int jj = j - 70;
        if (jj < 64)       P[128 + jj] = acc;
        else if (jj == 64) P[192] = softplusf_(acc);
        else if (jj == 65) P[193] = sigmoidf_(acc);
        else if (jj <= 68) P[224 + (jj - 66)] = acc;
        else if (jj == 69) P[197] = 1.f + softplusf_(acc);
        else if (jj < 134) P[256 + (jj - 70)] = acc;
        else               P[320 + (jj - 134)] = acc;
    }
}

// ---------------- Cooperative mega-kernel (primary path) ----------------
// 512 blocks (2/CU), each owns 1024 rows of one batch. wgam stays in LDS.
__global__ void __launch_bounds__(256, 2)
k_main(const float* __restrict__ mem, float* __restrict__ ws,
       const float* __restrict__ W_o, const float* __restrict__ b_o,
       float* __restrict__ out) {
    cg::grid_group grid = cg::this_grid();
    int bc = blockIdx.x;              // 0..511
    int b = bc >> 4, slab = bc & 15;  // 16 slabs of 1024 rows per batch
    int tid = threadIdx.x;            // 0..255
    int r0 = slab * 1024;
    const float* P = ws + OFF_P + (size_t)b * 512;

    __shared__ float sh_kr[64], sh_kw[64];
    __shared__ float sh_er[1026], sh_ew[1026];
    __shared__ float sh_wgr[1024], sh_wgw[1024];
    __shared__ float par[8];
    __shared__ float lr[4], lw[4];
    __shared__ float4 red[256];
    __shared__ float sh_r[64];
    __shared__ float red2[256];

    // prologue (wave 0): stage keys, key norms, shift softmaxes
    if (tid < 64) {
        float kr = P[tid], kw = P[128 + tid];
        sh_kr[tid] = kr; sh_kw[tid] = kw;
        float nr = kr * kr, nw = kw * kw;
        #pragma unroll
        for (int off = 32; off >= 1; off >>= 1) {
            nr += __shfl_xor(nr, off);
            nw += __shfl_xor(nw, off);
        }
        if (tid == 0) {
            par[0] = 1.f / fmaxf(sqrtf(nr), EPSV);
            par[1] = 1.f / fmaxf(sqrtf(nw), EPSV);
            float s0 = softplusf_(P[96]), s1 = softplusf_(P[97]), s2 = softplusf_(P[98]);
            float mx = fmaxf(s0, fmaxf(s1, s2));
            float e0 = expf(s0 - mx), e1 = expf(s1 - mx), e2 = expf(s2 - mx);
            float si = 1.f / (e0 + e1 + e2);
            par[2] = e0 * si; par[3] = e1 * si; par[4] = e2 * si;
            s0 = softplusf_(P[224]); s1 = softplusf_(P[225]); s2 = softplusf_(P[226]);
            mx = fmaxf(s0, fmaxf(s1, s2));
            e0 = expf(s0 - mx); e1 = expf(s1 - mx); e2 = expf(s2 - mx);
            si = 1.f / (e0 + e1 + e2);
            par[5] = e0 * si; par[6] = e1 * si; par[7] = e2 * si;
        }
    }
    float beta_r = P[64], beta_w = P[192];
    float gamma_r = P[69], gamma_w = P[197];

    // halo rows r0-1 and r0+1024 (wave 0; par[] wave-coherent)
    if (tid < 32) {
        int grp = tid >> 4, c = tid & 15;
        int hrow = grp ? ((r0 + 1024) & (SS - 1)) : ((r0 - 1) & (SS - 1));
        float4 m4 = *(const float4*)(mem + ((size_t)b * SS + hrow) * 64 + c * 4);
        float4 kr4 = *(const float4*)(P + c * 4);
        float4 kw4 = *(const float4*)(P + 128 + c * 4);
        float dr = m4.x * kr4.x + m4.y * kr4.y + m4.z * kr4.z + m4.w * kr4.w;
        float dw = m4.x * kw4.x + m4.y * kw4.y + m4.z * kw4.z + m4.w * kw4.w;
        float n2 = m4.x * m4.x + m4.y * m4.y + m4.z * m4.z + m4.w * m4.w;
        #pragma unroll
        for (int off = 8; off >= 1; off >>= 1) {
            dr += __shfl_xor(dr, off);
            dw += __shfl_xor(dw, off);
            n2 += __shfl_xor(n2, off);
        }
        if (c == 0) {
            float imn = 1.f / fmaxf(sqrtf(n2), EPSV);
            int slot = grp ? 1025 : 0;
            sh_er[slot] = exp2f(1.44269504f * beta_r * (dr * par[0] * imn - 1.f));
            sh_ew[slot] = exp2f(1.44269504f * beta_w * (dw * par[1] * imn - 1.f));
        }
    }
    __syncthreads();
    float ikr = par[0], ikw = par[1];

    // scores: 4 lanes/row register-resident; wave w owns rows [w*256, w*256+256)
    int w = tid >> 6, lane = tid & 63;
    {
        int rw = lane >> 2, q = lane & 3;
        float4 kr0 = *(const float4*)(sh_kr + q * 16);
        float4 kr1 = *(const float4*)(sh_kr + q * 16 + 4);
        float4 kr2 = *(const float4*)(sh_kr + q * 16 + 8);
        float4 kr3 = *(const float4*)(sh_kr + q * 16 + 12);
        float4 kw0 = *(const float4*)(sh_kw + q * 16);
        float4 kw1 = *(const float4*)(sh_kw + q * 16 + 4);
        float4 kw2 = *(const float4*)(sh_kw + q * 16 + 8);
        float4 kw3 = *(const float4*)(sh_kw + q * 16 + 12);
        #pragma unroll 2
        for (int it = 0; it < 16; ++it) {
            int r = w * 256 + it * 16 + rw;     // 0..1023 slab-local
            const float4* rp = (const float4*)(mem + ((size_t)b * SS + r0 + r) * 64) + q * 4;
            float4 a0 = rp[0], a1 = rp[1], a2 = rp[2], a3 = rp[3];
            float dr, dw, n2;
            dr = a0.x*kr0.x + a0.y*kr0.y + a0.z*kr0.z + a0.w*kr0.w;
            dr = fmaf(a1.x,kr1.x, fmaf(a1.y,kr1.y, fmaf(a1.z,kr1.z, fmaf(a1.w,kr1.w, dr))));
            dr = fmaf(a2.x,kr2.x, fmaf(a2.y,kr2.y, fmaf(a2.z,kr2.z, fmaf(a2.w,kr2.w, dr))));
            dr = fmaf(a3.x,kr3.x, fmaf(a3.y,kr3.y, fmaf(a3.z,kr3.z, fmaf(a3.w,kr3.w, dr))));
            dw = a0.x*kw0.x + a0.y*kw0.y + a0.z*kw0.z + a0.w*kw0.w;
            dw = fmaf(a1.x,kw1.x, fmaf(a1.y,kw1.y, fmaf(a1.z,kw1.z, fmaf(a1.w,kw1.w, dw))));
            dw = fmaf(a2.x,kw2.x, fmaf(a2.y,kw2.y, fmaf(a2.z,kw2.z, fmaf(a2.w,kw2.w, dw))));
            dw = fmaf(a3.x,kw3.x, fmaf(a3.y,kw3.y, fmaf(a3.z,kw3.z, fmaf(a3.w,kw3.w, dw))));
            n2 = a0.x*a0.x + a0.y*a0.y + a0.z*a0.z + a0.w*a0.w;
            n2 = fmaf(a1.x,a1.x, fmaf(a1.y,a1.y, fmaf(a1.z,a1.z, fmaf(a1.w,a1.w, n2))));
            n2 = fmaf(a2.x,a2.x, fmaf(a2.y,a2.y, fmaf(a2.z,a2.z, fmaf(a2.w,a2.w, n2))));
            n2 = fmaf(a3.x,a3.x, fmaf(a3.y,a3.y, fmaf(a3.z,a3.z, fmaf(a3.w,a3.w, n2))));
            dr += __shfl_xor(dr, 1); dr += __shfl_xor(dr, 2);
            dw += __shfl_xor(dw, 1); dw += __shfl_xor(dw, 2);
            n2 += __shfl_xor(n2, 1); n2 += __shfl_xor(n2, 2);
            if (q == 0) {
                float imn = 1.f / fmaxf(sqrtf(n2), EPSV);
                sh_er[1 + r] = exp2f(1.44269504f * beta_r * (dr * ikr * imn - 1.f));
                sh_ew[1 + r] = exp2f(1.44269504f * beta_w * (dw * ikw * imn - 1.f));
            }
        }
    }
    __syncthreads();

    // conv + sharpen (4 rows/thread), wgam stays in LDS
    float sumr = 0.f, sumw = 0.f;
    #pragma unroll
    for (int k2 = 0; k2 < 4; ++k2) {
        int row = tid + k2 * 256;
        float cvr = par[2] * sh_er[row] + par[3] * sh_er[row + 1] + par[4] * sh_er[row + 2];
        float cvw = par[5] * sh_ew[row] + par[6] * sh_ew[row + 1] + par[7] * sh_ew[row + 2];
        float wgr = exp2f(gamma_r * log2f(cvr));
        float wgw = exp2f(gamma_w * log2f(cvw));
        sh_wgr[row] = wgr; sh_wgw[row] = wgw;
        sumr += wgr; sumw += wgw;
    }
    #pragma unroll
    for (int off = 32; off >= 1; off >>= 1) {
        sumr += __shfl_xor(sumr, off);
        sumw += __shfl_xor(sumw, off);
    }
    if (lane == 0) { lr[w] = sumr; lw[w] = sumw; }
    __syncthreads();
    if (tid == 0) {
        ws[OFF_CSGR + b * 16 + slab] = lr[0] + lr[1] + lr[2] + lr[3];
        ws[OFF_CSGW + b * 16 + slab] = lw[0] + lw[1] + lw[2] + lw[3];
    }
    grid.sync();

    // global 1/sums
    float sr = 0.f, sw = 0.f;
    #pragma unroll
    for (int c = 0; c < 16; ++c) {
        sr += ws[OFF_CSGR + b * 16 + c];
        sw += ws[OFF_CSGW + b * 16 + c];
    }
    float isr = 1.f / sr, isw = 1.f / sw;

    // update: 16 lanes/row, wgam from LDS, nontemporal stores
    {
        int rowslot = tid >> 4, col = tid & 15;
        float4 er4 = *(const float4*)(P + 256 + col * 4);
        float4 ad4 = *(const float4*)(P + 320 + col * 4);
        const float* mbase = mem + ((size_t)b * SS + r0) * 64;
        float* nm = out + 2048 + ((size_t)b * SS + r0) * 64;
        float4 racc = {0.f, 0.f, 0.f, 0.f};
        for (int it = 0; it < 64; ++it) {
            int row = it * 16 + rowslot;
            float wr = sh_wgr[row] * isr;
            float ww = sh_wgw[row] * isw;
            float4 v = *(const float4*)(mbase + (size_t)row * 64 + col * 4);
            racc.x = fmaf(wr, v.x, racc.x);
            racc.y = fmaf(wr, v.y, racc.y);
            racc.z = fmaf(wr, v.z, racc.z);
            racc.w = fmaf(wr, v.w, racc.w);
            nf4 o4;
            o4.x = v.x * (1.f - ww * er4.x) + ww * ad4.x;
            o4.y = v.y * (1.f - ww * er4.y) + ww * ad4.y;
            o4.z = v.z * (1.f - ww * er4.z) + ww * ad4.z;
            o4.w = v.w * (1.f - ww * er4.w) + ww * ad4.w;
            __builtin_nontemporal_store(o4, (nf4*)(nm + (size_t)row * 64 + col * 4));
        }
        red[tid] = racc;
        __syncthreads();
        if (tid < 16) {
            float4 a = red[tid];
            for (int rs = 1; rs < 16; ++rs) {
                float4 t2 = red[rs * 16 + tid];
                a.x += t2.x; a.y += t2.y; a.z += t2.z; a.w += t2.w;
            }
            float* rp = ws + OFF_CRP + ((size_t)b * 16 + slab) * 64;
            rp[tid * 4 + 0] = a.x;
            rp[tid * 4 + 1] = a.y;
            rp[tid * 4 + 2] = a.z;
            rp[tid * 4 + 3] = a.w;
        }
    }
    grid.sync();

    // output phase: slab==0 blocks (one per batch)
    if (slab == 0) {
        int o = tid & 63, p = tid >> 6;
        if (p == 0) {
            float rs = 0.f;
            for (int c = 0; c < 16; ++c) rs += ws[OFF_CRP + ((size_t)b * 16 + c) * 64 + o];
            sh_r[o] = rs;
        }
        const float* h = ws + OFF_H + (size_t)b * 512;
        const float* wv = W_o + (size_t)o * 576;
        float acc = 0.f;
        for (int t = p * 128; t < p * 128 + 128; ++t) acc = fmaf(h[t], wv[t], acc);
        red2[tid] = acc;
        __syncthreads();
        if (p == 0) {
            float a = red2[o] + red2[64 + o] + red2[128 + o] + red2[192 + o] + b_o[o];
            for (int m = 0; m < 64; ++m) a = fmaf(sh_r[m], wv[512 + m], a);
            float mx = a;
            #pragma unroll
            for (int off = 32; off >= 1; off >>= 1) mx = fmaxf(mx, __shfl_xor(mx, off));
            float e = expf(a - mx);
            float sm = e;
            #pragma unroll
            for (int off = 32; off >= 1; off >>= 1) sm += __shfl_xor(sm, off);
            out[b * 64 + o] = e / sm;
        }
    }
}

// ---------------- Fallback path (proven R10 kernels) ----------------
#define PST 260
__global__ void k_scorewgam(const float* __restrict__ mem, float* __restrict__ ws) {
    int b = blockIdx.x >> 6;
    int chunk = blockIdx.x & 63;
    int tid = threadIdx.x;
    const float* P = ws + OFF_P + (size_t)b * 512;
    int row0 = chunk * 256;
    __shared__ float pdr[16 * PST], pdw[16 * PST], pn2[16 * PST];
    __shared__ float sh_er[258], sh_ew[258];
    __shared__ float par[8];
    __shared__ float lr[4], lw[4];
    if (tid < 64) {
        float kr = P[tid], kw = P[128 + tid];
        float nr = kr * kr, nw = kw * kw;
        #pragma unroll
        for (int off = 32; off >= 1; off >>= 1) {
            nr += __shfl_xor(nr, off);
            nw += __shfl_xor(nw, off);
        }
        if (tid == 0) {
            par[0] = 1.f / fmaxf(sqrtf(nr), EPSV);
            par[1] = 1.f / fmaxf(sqrtf(nw), EPSV);
            float s0 = softplusf_(P[96]), s1 = softplusf_(P[97]), s2 = softplusf_(P[98]);
            float mx = fmaxf(s0, fmaxf(s1, s2));
            float e0 = expf(s0 - mx), e1 = expf(s1 - mx), e2 = expf(s2 - mx);
            float si = 1.f / (e0 + e1 + e2);
            par[2] = e0 * si; par[3] = e1 * si; par[4] = e2 * si;
            s0 = softplusf_(P[224]); s1 = softplusf_(P[225]); s2 = softplusf_(P[226]);
            mx = fmaxf(s0, fmaxf(s1, s2));
            e0 = expf(s0 - mx); e1 = expf(s1 - mx); e2 = expf(s2 - mx);
            si = 1.f / (e0 + e1 + e2);
            par[5] = e0 * si; par[6] = e1 * si; par[7] = e2 * si;
        }
    }
    float beta_r = P[64], beta_w = P[192];
    float gamma_r = P[69], gamma_w = P[197];
    if (tid < 32) {
        int grp = tid >> 4, c = tid & 15;
        int hrow = grp ? ((row0 + 256) & (SS - 1)) : ((row0 - 1) & (SS - 1));
        float4 m4 = *(const float4*)(mem + ((size_t)b * SS + hrow) * 64 + c * 4);
        float4 kr4 = *(const float4*)(P + c * 4);
        float4 kw4 = *(const float4*)(P + 128 + c * 4);
        float dr = m4.x * kr4.x + m4.y * kr4.y + m4.z * kr4.z + m4.w * kr4.w;
        float dw = m4.x * kw4.x + m4.y * kw4.y + m4.z * kw4.z + m4.w * kw4.w;
        float n2 = m4.x * m4.x + m4.y * m4.y + m4.z * m4.z + m4.w * m4.w;
        #pragma unroll
        for (int off = 8; off >= 1; off >>= 1) {
            dr += __shfl_xor(dr, off);
            dw += __shfl_xor(dw, off);
            n2 += __shfl_xor(n2, off);
        }
        if (c == 0) {
            float imn = 1.f / fmaxf(sqrtf(n2), EPSV);
            int slot = grp ? 257 : 0;
            sh_er[slot] = exp2f(1.44269504f * beta_r * (dr * par[0] * imn - 1.f));
            sh_ew[slot] = exp2f(1.44269504f * beta_w * (dw * par[1] * imn - 1.f));
        }
    }
    int rowslot = tid >> 4, col = tid & 15;
    float4 kr4 = *(const float4*)(P + col * 4);
    float4 kw4 = *(const float4*)(P + 128 + col * 4);
    const float4* base = (const float4*)(mem + ((size_t)b * SS + row0) * 64) + tid;
    #pragma unroll
    for (int it = 0; it < 16; ++it) {
        float4 v = base[it * 256];
        int row = it * 16 + rowslot;
        pdr[col * PST + row] = v.x * kr4.x + v.y * kr4.y + v.z * kr4.z + v.w * kr4.w;
        pdw[col * PST + row] = v.x * kw4.x + v.y * kw4.y + v.z * kw4.z + v.w * kw4.w;
        pn2[col * PST + row] = v.x * v.x + v.y * v.y + v.z * v.z + v.w * v.w;
    }
    __syncthreads();
    {
        float a0, a1, a2, a3;
        a0 = pdr[0*PST+tid] + pdr[1*PST+tid];  a1 = pdr[2*PST+tid] + pdr[3*PST+tid];
        a2 = pdr[4*PST+tid] + pdr[5*PST+tid];  a3 = pdr[6*PST+tid] + pdr[7*PST+tid];
        float dr = (a0 + a1) + (a2 + a3);
        a0 = pdr[8*PST+tid] + pdr[9*PST+tid];  a1 = pdr[10*PST+tid] + pdr[11*PST+tid];
        a2 = pdr[12*PST+tid] + pdr[13*PST+tid]; a3 = pdr[14*PST+tid] + pdr[15*PST+tid];
        dr += (a0 + a1) + (a2 + a3);
        a0 = pdw[0*PST+tid] + pdw[1*PST+tid];  a1 = pdw[2*PST+tid] + pdw[3*PST+tid];
        a2 = pdw[4*PST+tid] + pdw[5*PST+tid];  a3 = pdw[6*PST+tid] + pdw[7*PST+tid];
        float dw = (a0 + a1) + (a2 + a3);
        a0 = pdw[8*PST+tid] + pdw[9*PST+tid];  a1 = pdw[10*PST+tid] + pdw[11*PST+tid];
        a2 = pdw[12*PST+tid] + pdw[13*PST+tid]; a3 = pdw[14*PST+tid] + pdw[15*PST+tid];
        dw += (a0 + a1) + (a2 + a3);
        a0 = pn2[0*PST+tid] + pn2[1*PST+tid];  a1 = pn2[2*PST+tid] + pn2[3*PST+tid];
        a2 = pn2[4*PST+tid] + pn2[5*PST+tid];  a3 = pn2[6*PST+tid] + pn2[7*PST+tid];
        float n2 = (a0 + a1) + (a2 + a3);
        a0 = pn2[8*PST+tid] + pn2[9*PST+tid];  a1 = pn2[10*PST+tid] + pn2[11*PST+tid];
        a2 = pn2[12*PST+tid] + pn2[13*PST+tid]; a3 = pn2[14*PST+tid] + pn2[15*PST+tid];
        n2 += (a0 + a1) + (a2 + a3);
        float imn = 1.f / fmaxf(sqrtf(n2), EPSV);
        sh_er[1 + tid] = exp2f(1.44269504f * beta_r * (dr * par[0] * imn - 1.f));
        sh_ew[1 + tid] = exp2f(1.44269504f * beta_w * (dw * par[1] * imn - 1.f));
    }
    __syncthreads();
    float cvr = par[2] * sh_er[tid] + par[3] * sh_er[tid + 1] + par[4] * sh_er[tid + 2];
    float cvw = par[5] * sh_ew[tid] + par[6] * sh_ew[tid + 1] + par[7] * sh_ew[tid + 2];
    float wgr = exp2f(gamma_r * log2f(cvr));
    float wgw = exp2f(gamma_w * log2f(cvw));
    ws[OFF_WGR + (size_t)b * SS + row0 + tid] = wgr;
    ws[OFF_WGW + (size_t)b * SS + row0 + tid] = wgw;
    int w = tid >> 6, lane = tid & 63;
    float rr = wgr, rw2 = wgw;
    #pragma unroll
    for (int off = 32; off >= 1; off >>= 1) {
        rr += __shfl_xor(rr, off);
        rw2 += __shfl_xor(rw2, off);
    }
    if (lane == 0) { lr[w] = rr; lw[w] = rw2; }
    __syncthreads();
    if (tid == 0) {
        ws[OFF_SGRP + b * 64 + chunk] = lr[0] + lr[1] + lr[2] + lr[3];
        ws[OFF_SGWP + b * 64 + chunk] = lw[0] + lw[1] + lw[2] + lw[3];
    }
}

__global__ void k_update(const float* __restrict__ mem, float* __restrict__ ws,
                         float* __restrict__ out) {
    int b = blockIdx.x >> 6, chunk = blockIdx.x & 63, tid = threadIdx.x;
    int rowslot = tid >> 4, col = tid & 15;
    const float* P = ws + OFF_P + (size_t)b * 512;
    float4 er4 = *(const float4*)(P + 256 + col * 4);
    float4 ad4 = *(const float4*)(P + 320 + col * 4);
    __shared__ float sinv[2];
    if (tid < 64) {
        float v = ws[OFF_SGRP + b * 64 + tid];
        #pragma unroll
        for (int off = 32; off >= 1; off >>= 1) v += __shfl_xor(v, off);
        if (tid == 0) sinv[0] = 1.f / v;
    } else if (tid < 128) {
        float v = ws[OFF_SGWP + b * 64 + (tid - 64)];
        #pragma unroll
        for (int off = 32; off >= 1; off >>= 1) v += __shfl_xor(v, off);
        if (tid == 64) sinv[1] = 1.f / v;
    }
    __syncthreads();
    float isr = sinv[0], isw = sinv[1];
    const float* wgr = ws + OFF_WGR + (size_t)b * SS;
    const float* wgw = ws + OFF_WGW + (size_t)b * SS;
    float* nm = out + 2048 + (size_t)b * SS * 64;
    float4 racc = {0.f, 0.f, 0.f, 0.f};
    int row0 = chunk * 256;
    for (int it = 0; it < 16; ++it) {
        int row = row0 + it * 16 + rowslot;
        float wr = wgr[row] * isr;
        float ww = wgw[row] * isw;
        float4 v = *(const float4*)(mem + ((size_t)b * SS + row) * 64 + col * 4);
        racc.x = fmaf(wr, v.x, racc.x);
        racc.y = fmaf(wr, v.y, racc.y);
        racc.z = fmaf(wr, v.z, racc.z);
        racc.w = fmaf(wr, v.w, racc.w);
        float4 o4;
        o4.x = v.x * (1.f - ww * er4.x) + ww * ad4.x;
        o4.y = v.y * (1.f - ww * er4.y) + ww * ad4.y;
        o4.z = v.z * (1.f - ww * er4.z) + ww * ad4.z;
        o4.w = v.w * (1.f - ww * er4.w) + ww * ad4.w;
        *(float4*)(nm + (size_t)row * 64 + col * 4) = o4;
    }
    __shared__ float4 red[256];
    red[tid] = racc;
    __syncthreads();
    if (tid < 16) {
        float4 a = red[tid];
        for (int rs = 1; rs < 16; ++rs) {
            float4 t2 = red[rs * 16 + tid];
            a.x += t2.x; a.y += t2.y; a.z += t2.z; a.w += t2.w;
        }
        float* rp = ws + OFF_RP + ((size_t)b * 64 + chunk) * 64;
        rp[tid * 4 + 0] = a.x;
        rp[tid * 4 + 1] = a.y;
        rp[tid * 4 + 2] = a.z;
        rp[tid * 4 + 3] = a.w;
    }
}

__global__ void k_out(const float* __restrict__ ws, const float* __restrict__ W_o,
                      const float* __restrict__ b_o, float* __restrict__ out) {
    int b = blockIdx.x, o = threadIdx.x;
    __shared__ float sh_r[64];
    float accr = 0.f;
    for (int c = 0; c < 64; ++c) accr += ws[OFF_RP + ((size_t)b * 64 + c) * 64 + o];
    sh_r[o] = accr;
    __syncthreads();
    const float* h = ws + OFF_H + (size_t)b * 512;
    const float* w = W_o + (size_t)o * 576;
    float acc = b_o[o];
    for (int t = 0; t < 512; t++) acc = fmaf(h[t], w[t], acc);
    for (int m = 0; m < 64; m++) acc = fmaf(sh_r[m], w[512 + m], acc);
    float mx = acc;
    #pragma unroll
    for (int off = 32; off >= 1; off >>= 1) mx = fmaxf(mx, __shfl_xor(mx, off));
    float e = expf(acc - mx);
    float sm = e;
    #pragma unroll
    for (int off = 32; off >= 1; off >>= 1) sm += __shfl_xor(sm, off);
    out[b * 64 + o] = e / sm;
}

extern "C" void kernel_launch(void* const* d_in, const int* in_sizes, int n_in,
                              void* d_out, int out_size, void* d_ws, size_t ws_size,
                              hipStream_t stream) {
    const float* x    = (const float*)d_in[0];
    const float* pdo  = (const float*)d_in[1];
    const float* prv  = (const float*)d_in[2];
    const float* mem  = (const float*)d_in[3];
    const float* W_ih = (const float*)d_in[4];
    // d_in[5] = W_hh (unused by reference math)
    const float* b_ih = (const float*)d_in[6];
    const float* b_hh = (const float*)d_in[7];
    const float* W_r  = (const float*)d_in[8];
    const float* b_r  = (const float*)d_in[9];
    const float* W_w  = (const float*)d_in[10];
    const float* b_w  = (const float*)d_in[11];
    const float* W_o  = (const float*)d_in[12];
    const float* b_o  = (const float*)d_in[13];
    float* out = (float*)d_out;
    float* ws  = (float*)d_ws;

    k_lstm<<<BB * 512 / 4, 256, 0, stream>>>(x, pdo, prv, W_ih, b_ih, b_hh, ws);
    k_heads<<<(BB * 268) / 4, 256, 0, stream>>>(W_r, b_r, W_w, b_w, ws);

    const float* memc = mem; float* wsc = ws;
    const float* Woc = W_o; const float* boc = b_o; float* outc = out;
    void* args[] = { (void*)&memc, (void*)&wsc, (void*)&Woc, (void*)&boc, (void*)&outc };
    hipError_t err = hipLaunchCooperativeKernel((const void*)k_main, dim3(BB * 16),
                                                dim3(256), args, 0, stream);
    if (err != hipSuccess) {
        // fallback: proven non-cooperative path (identical math)
        k_scorewgam<<<BB * 64, 256, 0, stream>>>(mem, ws);
        k_update<<<BB * 64, 256, 0, stream>>>(mem, ws, out);
        k_out<<<BB, 64, 0, stream>>>(ws, W_o, b_o, out);
    }
}

// Round 15
// 107.065 us; speedup vs baseline: 2.0905x; 2.0905x over previous
//
#include <hip/hip_runtime.h>
#include <hip/hip_bf16.h>
#include <math.h>

// Problem constants
#define BB 32
#define SS 16384
#define MM 64
#define HID 512
#define EPSV 1e-8f

typedef float nf4 __attribute__((ext_vector_type(4)));   // native vec for nt-store

// ws layout (in floats)
#define OFF_H    0                 // 32*512 h vectors
#define OFF_P    16384             // 32*512 per-batch params (sparse, see below)
#define OFF_SGRP 32768             // BB*64 per-chunk wgam_r partial sums
#define OFF_SGWP (OFF_SGRP + BB*64)
#define OFF_RP   (OFF_SGWP + BB*64)       // BB*64*64 per-chunk r partials
#define OFF_WGR  (OFF_RP + BB*64*64)      // BB*SS
#define OFF_WGW  (OFF_WGR + BB*SS)        // BB*SS; total ~4.9 MB
//
// P-region per-batch layout (512 floats):
//  [0..63]   k_r            [64] beta_r  [69] gamma_r   [96..98] raw shift_r
//  [128..191] k_w           [192] beta_w [197] gamma_w  [224..226] raw shift_w
//  [256..319] erase         [320..383] add

__device__ __forceinline__ float sigmoidf_(float x) { return 1.f / (1.f + expf(-x)); }
__device__ __forceinline__ float softplusf_(float x) {
    return (x > 0.f) ? x + log1pf(expf(-x)) : log1pf(expf(x));
}

// One wave per (b,t): h[b][t].
__global__ void k_lstm(const float* __restrict__ x, const float* __restrict__ pdo,
                       const float* __restrict__ prv,
                       const float* __restrict__ W_ih, const float* __restrict__ b_ih,
                       const float* __restrict__ b_hh, float* __restrict__ ws) {
    int wid = blockIdx.x * 4 + (threadIdx.x >> 6);   // 0 .. 32*512-1
    int lane = threadIdx.x & 63;
    int b = wid >> 9, t = wid & 511;
    float x0 = x[b * 64 + lane];
    float x1 = pdo[b * 64 + lane];
    float x2 = prv[b * 64 + lane];
    const float* wi = W_ih + (size_t)t * 192;
    const float* wg = W_ih + (size_t)(1024 + t) * 192;
    const float* wo = W_ih + (size_t)(1536 + t) * 192;
    float zi = x0 * wi[lane] + x1 * wi[64 + lane] + x2 * wi[128 + lane];
    float zg = x0 * wg[lane] + x1 * wg[64 + lane] + x2 * wg[128 + lane];
    float zo = x0 * wo[lane] + x1 * wo[64 + lane] + x2 * wo[128 + lane];
    #pragma unroll
    for (int off = 32; off >= 1; off >>= 1) {
        zi += __shfl_xor(zi, off);
        zg += __shfl_xor(zg, off);
        zo += __shfl_xor(zo, off);
    }
    if (lane == 0) {
        zi += b_ih[t] + b_hh[t];
        zg += b_ih[1024 + t] + b_hh[1024 + t];
        zo += b_ih[1536 + t] + b_hh[1536 + t];
        float c = sigmoidf_(zi) * tanhf(zg);
        ws[OFF_H + (size_t)b * 512 + t] = sigmoidf_(zo) * tanhf(c);
    }
}

// One wave per (b, head-row j): j<70 read head, else write head row j-70.
__global__ void k_heads(const float* __restrict__ W_r, const float* __restrict__ b_r,
                        const float* __restrict__ W_w, const float* __restrict__ b_w,
                        float* __restrict__ ws) {
    int wid = blockIdx.x * 4 + (threadIdx.x >> 6);   // 0 .. 32*268-1
    int lane = threadIdx.x & 63;
    int b = wid / 268, j = wid % 268;
    const float* h = ws + OFF_H + (size_t)b * 512;
    const float* wrow;
    float bias;
    if (j < 70) { wrow = W_r + (size_t)j * 512; bias = b_r[j]; }
    else        { wrow = W_w + (size_t)(j - 70) * 512; bias = b_w[j - 70]; }
    float acc = 0.f;
    #pragma unroll
    for (int c = 0; c < 8; c++) acc = fmaf(h[c * 64 + lane], wrow[c * 64 + lane], acc);
    #pragma unroll
    for (int off = 32; off >= 1; off >>= 1) acc += __shfl_xor(acc, off);
    if (lane != 0) return;
    acc += bias;
    float* P = ws + OFF_P + (size_t)b * 512;
    if (j < 70) {
        if (j < 64)       P[j] = acc;                       // k_r
        else if (j == 64) P[64] = softplusf_(acc);          // beta_r
        else if (j == 65) P[65] = sigmoidf_(acc);           // g_r (cancels; unused)
        else if (j <= 68) P[96 + (j - 66)] = acc;           // raw shift_r
        else              P[69] = 1.f + softplusf_(acc);    // gamma_r
    } else {
        int jj = j - 70;
        if (jj < 64)       P[128 + jj] = acc;               // k_w
        else if (jj == 64) P[192] = softplusf_(acc);        // beta_w
        else if (jj == 65) P[193] = sigmoidf_(acc);         // g_w (cancels; unused)
        else if (jj <= 68) P[224 + (jj - 66)] = acc;        // raw shift_w
        else if (jj == 69) P[197] = 1.f + softplusf_(acc);  // gamma_w
        else if (jj < 134) P[256 + (jj - 70)] = acc;        // erase
        else               P[320 + (jj - 134)] = acc;       // add
    }
}

// Fused scores+conv+sharpen (R10 structure, measured ~29.6 us warm).
#define PST 260   // partial-array row stride (260 % 32 == 4 -> conflict-free)
__global__ void k_scorewgam(const float* __restrict__ mem, float* __restrict__ ws) {
    int b = blockIdx.x >> 6;
    int chunk = blockIdx.x & 63;
    int tid = threadIdx.x;            // 0..255
    const float* P = ws + OFF_P + (size_t)b * 512;
    int row0 = chunk * 256;

    __shared__ float pdr[16 * PST], pdw[16 * PST], pn2[16 * PST];  // 49.9 KB
    __shared__ float sh_er[258], sh_ew[258];
    __shared__ float par[8];   // ikr, ikw, sr0..2, sw0..2
    __shared__ float lr[4], lw[4];

    // prologue on wave 0: key norms + shift softmaxes
    if (tid < 64) {
        float kr = P[tid], kw = P[128 + tid];
        float nr = kr * kr, nw = kw * kw;
        #pragma unroll
        for (int off = 32; off >= 1; off >>= 1) {
            nr += __shfl_xor(nr, off);
            nw += __shfl_xor(nw, off);
        }
        if (tid == 0) {
            par[0] = 1.f / fmaxf(sqrtf(nr), EPSV);
            par[1] = 1.f / fmaxf(sqrtf(nw), EPSV);
            float s0 = softplusf_(P[96]), s1 = softplusf_(P[97]), s2 = softplusf_(P[98]);
            float mx = fmaxf(s0, fmaxf(s1, s2));
            float e0 = expf(s0 - mx), e1 = expf(s1 - mx), e2 = expf(s2 - mx);
            float si = 1.f / (e0 + e1 + e2);
            par[2] = e0 * si; par[3] = e1 * si; par[4] = e2 * si;
            s0 = softplusf_(P[224]); s1 = softplusf_(P[225]); s2 = softplusf_(P[226]);
            mx = fmaxf(s0, fmaxf(s1, s2));
            e0 = expf(s0 - mx); e1 = expf(s1 - mx); e2 = expf(s2 - mx);
            si = 1.f / (e0 + e1 + e2);
            par[5] = e0 * si; par[6] = e1 * si; par[7] = e2 * si;
        }
    }
    float beta_r = P[64], beta_w = P[192];
    float gamma_r = P[69], gamma_w = P[197];

    // halo rows row0-1 and row0+256 (wave 0; par[] is wave-coherent here)
    if (tid < 32) {
        int grp = tid >> 4, c = tid & 15;
        int hrow = grp ? ((row0 + 256) & (SS - 1)) : ((row0 - 1) & (SS - 1));
        float4 m4 = *(const float4*)(mem + ((size_t)b * SS + hrow) * 64 + c * 4);
        float4 kr4 = *(const float4*)(P + c * 4);
        float4 kw4 = *(const float4*)(P + 128 + c * 4);
        float dr = m4.x * kr4.x + m4.y * kr4.y + m4.z * kr4.z + m4.w * kr4.w;
        float dw = m4.x * kw4.x + m4.y * kw4.y + m4.z * kw4.z + m4.w * kw4.w;
        float n2 = m4.x * m4.x + m4.y * m4.y + m4.z * m4.z + m4.w * m4.w;
        #pragma unroll
        for (int off = 8; off >= 1; off >>= 1) {
            dr += __shfl_xor(dr, off);
            dw += __shfl_xor(dw, off);
            n2 += __shfl_xor(n2, off);
        }
        if (c == 0) {
            float imn = 1.f / fmaxf(sqrtf(n2), EPSV);
            int slot = grp ? 257 : 0;
            sh_er[slot] = exp2f(1.44269504f * beta_r * (dr * par[0] * imn - 1.f));
            sh_ew[slot] = exp2f(1.44269504f * beta_w * (dw * par[1] * imn - 1.f));
        }
    }

    // phase A: coalesced loop; store per-(row,col) partials to LDS
    int rowslot = tid >> 4, col = tid & 15;
    float4 kr4 = *(const float4*)(P + col * 4);
    float4 kw4 = *(const float4*)(P + 128 + col * 4);
    const float4* base = (const float4*)(mem + ((size_t)b * SS + row0) * 64) + tid;
    #pragma unroll
    for (int it = 0; it < 16; ++it) {
        float4 v = base[it * 256];
        int row = it * 16 + rowslot;
        pdr[col * PST + row] = v.x * kr4.x + v.y * kr4.y + v.z * kr4.z + v.w * kr4.w;
        pdw[col * PST + row] = v.x * kw4.x + v.y * kw4.y + v.z * kw4.z + v.w * kw4.w;
        pn2[col * PST + row] = v.x * v.x + v.y * v.y + v.z * v.z + v.w * v.w;
    }
    __syncthreads();

    // phase B: thread == row; 48 independent b32 reads, register tree sums
    {
        float a0, a1, a2, a3;
        a0 = pdr[0*PST+tid] + pdr[1*PST+tid];  a1 = pdr[2*PST+tid] + pdr[3*PST+tid];
        a2 = pdr[4*PST+tid] + pdr[5*PST+tid];  a3 = pdr[6*PST+tid] + pdr[7*PST+tid];
        float dr = (a0 + a1) + (a2 + a3);
        a0 = pdr[8*PST+tid] + pdr[9*PST+tid];  a1 = pdr[10*PST+tid] + pdr[11*PST+tid];
        a2 = pdr[12*PST+tid] + pdr[13*PST+tid]; a3 = pdr[14*PST+tid] + pdr[15*PST+tid];
        dr += (a0 + a1) + (a2 + a3);
        a0 = pdw[0*PST+tid] + pdw[1*PST+tid];  a1 = pdw[2*PST+tid] + pdw[3*PST+tid];
        a2 = pdw[4*PST+tid] + pdw[5*PST+tid];  a3 = pdw[6*PST+tid] + pdw[7*PST+tid];
        float dw = (a0 + a1) + (a2 + a3);
        a0 = pdw[8*PST+tid] + pdw[9*PST+tid];  a1 = pdw[10*PST+tid] + pdw[11*PST+tid];
        a2 = pdw[12*PST+tid] + pdw[13*PST+tid]; a3 = pdw[14*PST+tid] + pdw[15*PST+tid];
        dw += (a0 + a1) + (a2 + a3);
        a0 = pn2[0*PST+tid] + pn2[1*PST+tid];  a1 = pn2[2*PST+tid] + pn2[3*PST+tid];
        a2 = pn2[4*PST+tid] + pn2[5*PST+tid];  a3 = pn2[6*PST+tid] + pn2[7*PST+tid];
        float n2 = (a0 + a1) + (a2 + a3);
        a0 = pn2[8*PST+tid] + pn2[9*PST+tid];  a1 = pn2[10*PST+tid] + pn2[11*PST+tid];
        a2 = pn2[12*PST+tid] + pn2[13*PST+tid]; a3 = pn2[14*PST+tid] + pn2[15*PST+tid];
        n2 += (a0 + a1) + (a2 + a3);
        float imn = 1.f / fmaxf(sqrtf(n2), EPSV);
        sh_er[1 + tid] = exp2f(1.44269504f * beta_r * (dr * par[0] * imn - 1.f));
        sh_ew[1 + tid] = exp2f(1.44269504f * beta_w * (dw * par[1] * imn - 1.f));
    }
    __syncthreads();

    // conv + sharpen for row s = row0 + tid (fast pow: base > 0)
    float cvr = par[2] * sh_er[tid] + par[3] * sh_er[tid + 1] + par[4] * sh_er[tid + 2];
    float cvw = par[5] * sh_ew[tid] + par[6] * sh_ew[tid + 1] + par[7] * sh_ew[tid + 2];
    float wgr = exp2f(gamma_r * log2f(cvr));
    float wgw = exp2f(gamma_w * log2f(cvw));
    ws[OFF_WGR + (size_t)b * SS + row0 + tid] = wgr;
    ws[OFF_WGW + (size_t)b * SS + row0 + tid] = wgw;

    int w = tid >> 6, lane = tid & 63;
    float rr = wgr, rw2 = wgw;
    #pragma unroll
    for (int off = 32; off >= 1; off >>= 1) {
        rr += __shfl_xor(rr, off);
        rw2 += __shfl_xor(rw2, off);
    }
    if (lane == 0) { lr[w] = rr; lw[w] = rw2; }
    __syncthreads();
    if (tid == 0) {
        ws[OFF_SGRP + b * 64 + chunk] = lr[0] + lr[1] + lr[2] + lr[3];
        ws[OFF_SGWP + b * 64 + chunk] = lw[0] + lw[1] + lw[2] + lw[3];
    }
}

// Final weights; r partials; new_mem = mem*(1-w_w*e)+w_w*a.
// Nontemporal stores for new_mem: write-once stream, keeps mem L3-resident.
__global__ void k_update(const float* __restrict__ mem, float* __restrict__ ws,
                         float* __restrict__ out) {
    int b = blockIdx.x >> 6, chunk = blockIdx.x & 63, tid = threadIdx.x;
    int rowslot = tid >> 4, col = tid & 15;
    const float* P = ws + OFF_P + (size_t)b * 512;
    float4 er4 = *(const float4*)(P + 256 + col * 4);
    float4 ad4 = *(const float4*)(P + 320 + col * 4);

    // reduce per-chunk wgam sums -> 1/sum
    __shared__ float sinv[2];
    if (tid < 64) {
        float v = ws[OFF_SGRP + b * 64 + tid];
        #pragma unroll
        for (int off = 32; off >= 1; off >>= 1) v += __shfl_xor(v, off);
        if (tid == 0) sinv[0] = 1.f / v;
    } else if (tid < 128) {
        float v = ws[OFF_SGWP + b * 64 + (tid - 64)];
        #pragma unroll
        for (int off = 32; off >= 1; off >>= 1) v += __shfl_xor(v, off);
        if (tid == 64) sinv[1] = 1.f / v;
    }
    __syncthreads();
    float isr = sinv[0], isw = sinv[1];

    const float* wgr = ws + OFF_WGR + (size_t)b * SS;
    const float* wgw = ws + OFF_WGW + (size_t)b * SS;
    float* nm = out + 2048 + (size_t)b * SS * 64;
    float4 racc = {0.f, 0.f, 0.f, 0.f};
    int row0 = chunk * 256;
    for (int it = 0; it < 16; ++it) {
        int row = row0 + it * 16 + rowslot;
        float wr = wgr[row] * isr;
        float ww = wgw[row] * isw;
        float4 v = *(const float4*)(mem + ((size_t)b * SS + row) * 64 + col * 4);
        racc.x = fmaf(wr, v.x, racc.x);
        racc.y = fmaf(wr, v.y, racc.y);
        racc.z = fmaf(wr, v.z, racc.z);
        racc.w = fmaf(wr, v.w, racc.w);
        nf4 o4;
        o4.x = v.x * (1.f - ww * er4.x) + ww * ad4.x;
        o4.y = v.y * (1.f - ww * er4.y) + ww * ad4.y;
        o4.z = v.z * (1.f - ww * er4.z) + ww * ad4.z;
        o4.w = v.w * (1.f - ww * er4.w) + ww * ad4.w;
        __builtin_nontemporal_store(o4, (nf4*)(nm + (size_t)row * 64 + col * 4));
    }
    __shared__ float4 red[256];
    red[tid] = racc;
    __syncthreads();
    if (tid < 16) {
        float4 a = red[tid];
        for (int rs = 1; rs < 16; ++rs) {
            float4 t2 = red[rs * 16 + tid];
            a.x += t2.x; a.y += t2.y; a.z += t2.z; a.w += t2.w;
        }
        float* rp = ws + OFF_RP + ((size_t)b * 64 + chunk) * 64;
        rp[tid * 4 + 0] = a.x;
        rp[tid * 4 + 1] = a.y;
        rp[tid * 4 + 2] = a.z;
        rp[tid * 4 + 3] = a.w;
    }
}

// output = softmax(concat(h, r) @ W_o.T + b_o); 256 threads/batch (4-way dot split).
__global__ void k_out(const float* __restrict__ ws, const float* __restrict__ W_o,
                      const float* __restrict__ b_o, float* __restrict__ out) {
    int b = blockIdx.x;
    int tid = threadIdx.x;            // 0..255
    int o = tid & 63, p = tid >> 6;
    __shared__ float sh_r[64];
    __shared__ float red2[256];
    const float* h = ws + OFF_H + (size_t)b * 512;
    const float* wv = W_o + (size_t)o * 576;
    float acc = 0.f;
    for (int t = p * 128; t < p * 128 + 128; ++t) acc = fmaf(h[t], wv[t], acc);
    red2[tid] = acc;
    if (p == 0) {
        float rs = 0.f;
        for (int c = 0; c < 64; ++c) rs += ws[OFF_RP + ((size_t)b * 64 + c) * 64 + o];
        sh_r[o] = rs;
    }
    __syncthreads();
    if (p == 0) {
        float a = red2[o] + red2[64 + o] + red2[128 + o] + red2[192 + o] + b_o[o];
        for (int m = 0; m < 64; ++m) a = fmaf(sh_r[m], wv[512 + m], a);
        float mx = a;
        #pragma unroll
        for (int off = 32; off >= 1; off >>= 1) mx = fmaxf(mx, __shfl_xor(mx, off));
        float e = expf(a - mx);
        float sm = e;
        #pragma unroll
        for (int off = 32; off >= 1; off >>= 1) sm += __shfl_xor(sm, off);
        out[b * 64 + o] = e / sm;
    }
}

extern "C" void kernel_launch(void* const* d_in, const int* in_sizes, int n_in,
                              void* d_out, int out_size, void* d_ws, size_t ws_size,
                              hipStream_t stream) {
    const float* x    = (const float*)d_in[0];
    const float* pdo  = (const float*)d_in[1];
    const float* prv  = (const float*)d_in[2];
    const float* mem  = (const float*)d_in[3];
    const float* W_ih = (const float*)d_in[4];
    // d_in[5] = W_hh (unused by reference math)
    const float* b_ih = (const float*)d_in[6];
    const float* b_hh = (const float*)d_in[7];
    const float* W_r  = (const float*)d_in[8];
    const float* b_r  = (const float*)d_in[9];
    const float* W_w  = (const float*)d_in[10];
    const float* b_w  = (const float*)d_in[11];
    const float* W_o  = (const float*)d_in[12];
    const float* b_o  = (const float*)d_in[13];
    float* out = (float*)d_out;
    float* ws  = (float*)d_ws;

    k_lstm<<<BB * 512 / 4, 256, 0, stream>>>(x, pdo, prv, W_ih, b_ih, b_hh, ws);
    k_heads<<<(BB * 268) / 4, 256, 0, stream>>>(W_r, b_r, W_w, b_w, ws);
    k_scorewgam<<<BB * 64, 256, 0, stream>>>(mem, ws);
    k_update<<<BB * 64, 256, 0, stream>>>(mem, ws, out);
    k_out<<<BB, 256, 0, stream>>>(ws, W_o, b_o, out);
}